// Round 8
// baseline (251.663 us; speedup 1.0000x reference)
//
#include <hip/hip_runtime.h>

// SupProtoConLoss on MI355X — round 8.
// R7 post-mortem: conflicts fixed (33.5M->8.39M baseline), 110.5us. Residual:
// ~800 cyc/iter stall — B-stage loads issued immediately BEFORE the draining
// barrier (prefetch distance ~0), all CU waves in lockstep.
// Round 8: block owns the CU. 512 threads (8 waves, same 8 waves/CU as R7),
// As 64KB + double-buffered Bs 2x32KB = 128KB LDS, JT=512. Flat 64-iter loop,
// ONE barrier/iter: barrier -> issue stage(it+1 -> buf^1) -> compute(it, buf).
// At the next barrier the prefetch has a full compute phase (~600 cyc) in
// flight -> vmcnt(0) drain ~free. R2's dbuf failure was VGPR-driven residency
// loss; here residency is LDS-bound and unchanged.

#define NROW 8192
#define DDIM 512
#define NCLS 100
#define PANEL 64
#define JT 512  // cols per j-tile (8 waves x 64)
#define BK 32

typedef float f32x4 __attribute__((ext_vector_type(4)));
typedef short s16x8 __attribute__((ext_vector_type(8)));

#define GLOBAL_AS __attribute__((address_space(1)))
#define LDS_AS __attribute__((address_space(3)))

__device__ __forceinline__ unsigned short f2bf(float x) {
  unsigned int u = __builtin_bit_cast(unsigned int, x);
  u += 0x7FFFu + ((u >> 16) & 1u);  // round-to-nearest-even
  return (unsigned short)(u >> 16);
}

// One wave per row: L2-norm, scale, cast to bf16; label histogram.
__global__ void __launch_bounds__(256) k_prep(
    const float* __restrict__ reps, const int* __restrict__ labels,
    unsigned short* __restrict__ Rb, int* __restrict__ cnt) {
  const int wave = threadIdx.x >> 6;
  const int lane = threadIdx.x & 63;
  const int row = blockIdx.x * 4 + wave;
  const float* r = reps + (size_t)row * DDIM;
  float4 v0 = *(const float4*)(r + lane * 4);
  float4 v1 = *(const float4*)(r + 256 + lane * 4);
  float ss = v0.x * v0.x + v0.y * v0.y + v0.z * v0.z + v0.w * v0.w +
             v1.x * v1.x + v1.y * v1.y + v1.z * v1.z + v1.w * v1.w;
#pragma unroll
  for (int m = 1; m < 64; m <<= 1) ss += __shfl_xor(ss, m);
  const float scale = 1.0f / sqrtf(ss);  // norms ~22.6; 1e-8 clamp unreachable
  ushort4 a, b;
  a.x = f2bf(v0.x * scale); a.y = f2bf(v0.y * scale);
  a.z = f2bf(v0.z * scale); a.w = f2bf(v0.w * scale);
  b.x = f2bf(v1.x * scale); b.y = f2bf(v1.y * scale);
  b.z = f2bf(v1.z * scale); b.w = f2bf(v1.w * scale);
  *(ushort4*)(Rb + (size_t)row * DDIM + lane * 4) = a;
  *(ushort4*)(Rb + (size_t)row * DDIM + 256 + lane * 4) = b;
  if (lane == 0) atomicAdd(&cnt[labels[row]], 1);
}

// Block = 64-row panel (p = bx>>2) x 2048-col slice (s = bx&3), 8 waves.
// Per jt (4 of them): wave covers 64 rows x 64 cols = 4a x 4b of 16x16x32.
__global__ void __launch_bounds__(512) k_row(
    const unsigned short* __restrict__ Rb, const int* __restrict__ labels,
    float* __restrict__ row_pos, float* __restrict__ row_neg) {
  const int bx = blockIdx.x;
  const int p = bx >> 2;   // row panel 0..127
  const int s = bx & 3;    // j slice 0..3 (fixed per XCD under %8 dispatch)
  const int i0 = p * PANEL;
  const int j0s = s * 2048;

  // As chunk-major [ch][row][k-in-chunk] (row stride 64B); Bs double-buffered.
  __shared__ __attribute__((aligned(16))) unsigned short As[16][PANEL][BK];  // 64 KB
  __shared__ __attribute__((aligned(16))) unsigned short Bs[2][JT * BK];     // 64 KB

  const int tid = threadIdx.x;
  const int lane = tid & 63;
  const int wave = tid >> 6;
  const int quad = lane >> 4, c16 = lane & 15;

  // ---- Stage A panel once, chunk-major: 64 instrs, 8 per wave.
#pragma unroll
  for (int t = 0; t < 8; ++t) {
    const int ii = wave * 8 + t;         // wave-uniform, 0..63
    const int ch = ii >> 2;
    const int rg = (ii & 3) * 16;
    const unsigned short* src =
        Rb + (size_t)(i0 + rg + (lane >> 2)) * DDIM + ch * BK + (lane & 3) * 8;
    __builtin_amdgcn_global_load_lds(
        (GLOBAL_AS void*)const_cast<unsigned short*>(src),
        (LDS_AS void*)(&As[ch][rg][0]), 16, 0, 0);
  }

  // B-stage for flat iteration it (jt = it>>4, ch = it&15) into buf.
  // 2048 chunks of 16B; 4 instrs per wave.
  auto stageB = [&](int it, int buf) {
    const int j0 = j0s + (it >> 4) * JT;
    const int ch = it & 15;
#pragma unroll
    for (int t = 0; t < 4; ++t) {
      const int cb = wave * 256 + t * 64;  // wave-uniform chunk base
      const int sl = cb + lane;            // jcol = sl>>2, kc = sl&3
      const unsigned short* src =
          Rb + (size_t)(j0 + (sl >> 2)) * DDIM + ch * BK + (sl & 3) * 8;
      __builtin_amdgcn_global_load_lds(
          (GLOBAL_AS void*)const_cast<unsigned short*>(src),
          (LDS_AS void*)(&Bs[buf][0] + cb * 8), 16, 0, 0);
    }
  };

  // Per-lane row labels and running row sums (live across the whole sweep).
  int li16[16];
  float ps16[16], ns16[16];
#pragma unroll
  for (int a = 0; a < 4; ++a)
#pragma unroll
    for (int r = 0; r < 4; ++r) {
      li16[a * 4 + r] = labels[i0 + a * 16 + quad * 4 + r];
      ps16[a * 4 + r] = 0.0f;
      ns16[a * 4 + r] = 0.0f;
    }

  const float C0 = -5.0f + 1e-7f;  // s = 5g - 5 + 1e-7 (static shift S=10)

  stageB(0, 0);  // prologue

  f32x4 acc[4][4];
  int lj[4], gj[4];

  for (int it = 0; it < 64; ++it) {
    const int ch = it & 15;
    if (ch == 0) {
      const int j0 = j0s + (it >> 4) * JT;
#pragma unroll
      for (int b = 0; b < 4; ++b) {
        gj[b] = j0 + wave * 64 + b * 16 + c16;
        lj[b] = labels[gj[b]];  // needed only at ch==15 — latency hidden
      }
#pragma unroll
      for (int a = 0; a < 4; ++a)
#pragma unroll
        for (int b = 0; b < 4; ++b) acc[a][b] = (f32x4)0.0f;
    }

    __syncthreads();  // drains stage(it) (in flight for a full compute phase)
    if (it + 1 < 64) stageB(it + 1, (it + 1) & 1);

    const unsigned short* Bb = &Bs[it & 1][0];
    s16x8 af[4], bfr[4];
#pragma unroll
    for (int a = 0; a < 4; ++a)
      af[a] = *(const s16x8*)(&As[ch][a * 16 + c16][quad * 8]);
#pragma unroll
    for (int b = 0; b < 4; ++b)
      bfr[b] = *(const s16x8*)(Bb + (wave * 64 + b * 16 + c16) * BK + quad * 8);
#pragma unroll
    for (int a = 0; a < 4; ++a)
#pragma unroll
      for (int b = 0; b < 4; ++b)
        acc[a][b] = __builtin_amdgcn_mfma_f32_16x16x32_bf16(af[a], bfr[b],
                                                            acc[a][b], 0, 0, 0);

    if (ch == 15) {
      // Fold this j-tile into register row sums (prefetch stays in flight).
#pragma unroll
      for (int a = 0; a < 4; ++a) {
#pragma unroll
        for (int r = 0; r < 4; ++r) {
          const int gi = i0 + a * 16 + quad * 4 + r;
          const int li = li16[a * 4 + r];
          float ps = 0.0f, ns = 0.0f;
#pragma unroll
          for (int b = 0; b < 4; ++b) {
            const float g = acc[a][b][r];
            const float sv = fmaf(g, 5.0f, C0);
            const float ev = __expf(sv);
            const bool same = (li == lj[b]);
            ps += (same && gi != gj[b]) ? sv : 0.0f;
            ns += same ? 0.0f : ev;
          }
          ps16[a * 4 + r] += ps;
          ns16[a * 4 + r] += ns;
        }
      }
    }
  }

  // ---- Block epilogue: reduce per-lane sums -> 64 rows, 2 atomics each.
  __syncthreads();                 // sweep done; Bs reusable as scratch
  float* rp = (float*)&Bs[0][0];   // 64 floats
  float* rn = rp + 64;
  if (tid < 128) rp[tid] = 0.0f;   // zeros rp[0..63] and rn[0..63]
  __syncthreads();
#pragma unroll
  for (int a = 0; a < 4; ++a) {
#pragma unroll
    for (int r = 0; r < 4; ++r) {
      float ps = ps16[a * 4 + r], ns = ns16[a * 4 + r];
#pragma unroll
      for (int m = 1; m < 16; m <<= 1) {  // reduce across the 16 c16 lanes
        ps += __shfl_xor(ps, m);
        ns += __shfl_xor(ns, m);
      }
      if (c16 == 0) {  // 8-way wave contention, once per block: trivial
        atomicAdd(&rp[a * 16 + quad * 4 + r], ps);
        atomicAdd(&rn[a * 16 + quad * 4 + r], ns);
      }
    }
  }
  __syncthreads();
  if (tid < 64) {
    atomicAdd(&row_pos[i0 + tid], rp[tid]);   // 4 adds per address chip-wide
    atomicAdd(&row_neg[i0 + tid], rn[tid]);
  }
}

__global__ void __launch_bounds__(512) k_final(
    const float* __restrict__ row_pos, const float* __restrict__ row_neg,
    const int* __restrict__ labels, const int* __restrict__ cnt,
    float* __restrict__ out) {
  __shared__ float ssum[8];
  __shared__ float scnt[8];
  const int tid = threadIdx.x;
  float lsum = 0.0f, lcnt = 0.0f;
  for (int i = tid; i < NROW; i += 512) {
    const float c = (float)(cnt[labels[i]] - 1);
    const float pos = row_pos[i] / (c + 1e-8f);
    const float loss = -pos + logf(row_neg[i] + 1e-8f);
    if (loss > 0.0f) { lsum += loss; lcnt += 1.0f; }
  }
#pragma unroll
  for (int m = 1; m < 64; m <<= 1) {
    lsum += __shfl_xor(lsum, m);
    lcnt += __shfl_xor(lcnt, m);
  }
  if ((tid & 63) == 0) { ssum[tid >> 6] = lsum; scnt[tid >> 6] = lcnt; }
  __syncthreads();
  if (tid == 0) {
    float S = 0.0f, C = 0.0f;
#pragma unroll
    for (int w = 0; w < 8; ++w) { S += ssum[w]; C += scnt[w]; }
    out[0] = S / (C + 1e-8f);
  }
}

extern "C" void kernel_launch(void* const* d_in, const int* in_sizes, int n_in,
                              void* d_out, int out_size, void* d_ws, size_t ws_size,
                              hipStream_t stream) {
  const float* reps = (const float*)d_in[0];
  const int* labels = (const int*)d_in[1];
  float* out = (float*)d_out;
  char* ws = (char*)d_ws;
  // ws layout: Rb (bf16 normalized reps, 8 MiB) | row_pos | row_neg | cnt
  unsigned short* Rb = (unsigned short*)ws;
  float* row_pos = (float*)(ws + (size_t)NROW * DDIM * 2);
  float* row_neg = row_pos + NROW;
  int* cnt = (int*)(row_neg + NROW);

  // row_pos | row_neg | cnt are contiguous: one async memset zeroes all three.
  (void)hipMemsetAsync(row_pos, 0, (size_t)(2 * NROW + NCLS) * 4, stream);
  k_prep<<<NROW / 4, 256, 0, stream>>>(reps, labels, Rb, cnt);
  k_row<<<512, 512, 0, stream>>>(Rb, labels, row_pos, row_neg);
  k_final<<<1, 512, 0, stream>>>(row_pos, row_neg, labels, cnt, out);
  (void)in_sizes; (void)n_in; (void)out_size; (void)ws_size;
}

// Round 9
// 247.801 us; speedup vs baseline: 1.0156x; 1.0156x over previous
//
#include <hip/hip_runtime.h>

// SupProtoConLoss on MI355X — round 9.
// R8 post-mortem: single 512-thread block/CU removed inter-block overlap (the
// actual latency-hiding mechanism, m114) -> regression. R2+R8 agree: in-block
// pipelining that costs block independence loses to inter-block TLP.
// Key insight: B has ZERO cross-wave reuse in this block shape (each Bs elem
// feeds exactly one lane). LDS-staging B bought nothing and cost 2 barriers +
// 4 global_load_lds + ds_reads per iter. A (4-wave reuse) stays in LDS.
// Round 9 = R7 shell (256 thr, As 64KB chunk-major staged once, 2 blocks/CU)
// with a BARRIER-FREE K-loop: B fragments loaded global->VGPR directly,
// per-jt base addresses + immediate offsets (ch*64B < 4KB), ch-loop unrolled,
// compiler pipelines with partial vmcnt; one __syncthreads per block total.

#define NROW 8192
#define DDIM 512
#define NCLS 100
#define PANEL 64
#define JT 256  // cols per j-tile (4 waves x 64)
#define BK 32

typedef float f32x4 __attribute__((ext_vector_type(4)));
typedef short s16x8 __attribute__((ext_vector_type(8)));

#define GLOBAL_AS __attribute__((address_space(1)))
#define LDS_AS __attribute__((address_space(3)))

__device__ __forceinline__ unsigned short f2bf(float x) {
  unsigned int u = __builtin_bit_cast(unsigned int, x);
  u += 0x7FFFu + ((u >> 16) & 1u);  // round-to-nearest-even
  return (unsigned short)(u >> 16);
}

// One wave per row: L2-norm, scale, cast to bf16; label histogram.
__global__ void __launch_bounds__(256) k_prep(
    const float* __restrict__ reps, const int* __restrict__ labels,
    unsigned short* __restrict__ Rb, int* __restrict__ cnt) {
  const int wave = threadIdx.x >> 6;
  const int lane = threadIdx.x & 63;
  const int row = blockIdx.x * 4 + wave;
  const float* r = reps + (size_t)row * DDIM;
  float4 v0 = *(const float4*)(r + lane * 4);
  float4 v1 = *(const float4*)(r + 256 + lane * 4);
  float ss = v0.x * v0.x + v0.y * v0.y + v0.z * v0.z + v0.w * v0.w +
             v1.x * v1.x + v1.y * v1.y + v1.z * v1.z + v1.w * v1.w;
#pragma unroll
  for (int m = 1; m < 64; m <<= 1) ss += __shfl_xor(ss, m);
  const float scale = 1.0f / sqrtf(ss);  // norms ~22.6; 1e-8 clamp unreachable
  ushort4 a, b;
  a.x = f2bf(v0.x * scale); a.y = f2bf(v0.y * scale);
  a.z = f2bf(v0.z * scale); a.w = f2bf(v0.w * scale);
  b.x = f2bf(v1.x * scale); b.y = f2bf(v1.y * scale);
  b.z = f2bf(v1.z * scale); b.w = f2bf(v1.w * scale);
  *(ushort4*)(Rb + (size_t)row * DDIM + lane * 4) = a;
  *(ushort4*)(Rb + (size_t)row * DDIM + 256 + lane * 4) = b;
  if (lane == 0) atomicAdd(&cnt[labels[row]], 1);
}

// Block = 64-row panel (p = bx>>2) x 2048-col slice (s = bx&3), 4 waves.
// Wave tile per jt: 64 rows x 64 cols = 4a x 4b of 16x16x32 MFMA.
__global__ void __launch_bounds__(256) k_row(
    const unsigned short* __restrict__ Rb, const int* __restrict__ labels,
    float* __restrict__ row_pos, float* __restrict__ row_neg) {
  const int bx = blockIdx.x;
  const int p = bx >> 2;   // row panel 0..127
  const int s = bx & 3;    // j slice 0..3 (fixed per XCD under %8 dispatch)
  const int i0 = p * PANEL;
  const int j0s = s * 2048;

  // As chunk-major [ch][row][k-in-chunk] (row stride 64B). 64 KB.
  __shared__ __attribute__((aligned(16))) unsigned short As[16][PANEL][BK];
  __shared__ float red[128];  // epilogue scratch

  const int tid = threadIdx.x;
  const int lane = tid & 63;
  const int wave = tid >> 6;
  const int quad = lane >> 4, c16 = lane & 15;

  // ---- Stage A panel once, chunk-major: 64 instrs, 16 per wave.
#pragma unroll
  for (int t = 0; t < 16; ++t) {
    const int ii = wave * 16 + t;        // wave-uniform, 0..63
    const int ch = ii >> 2;
    const int rg = (ii & 3) * 16;
    const unsigned short* src =
        Rb + (size_t)(i0 + rg + (lane >> 2)) * DDIM + ch * BK + (lane & 3) * 8;
    __builtin_amdgcn_global_load_lds(
        (GLOBAL_AS void*)const_cast<unsigned short*>(src),
        (LDS_AS void*)(&As[ch][rg][0]), 16, 0, 0);
  }

  // Per-lane row labels and running row sums (live across the whole sweep).
  int li16[16];
  float ps16[16], ns16[16];
#pragma unroll
  for (int a = 0; a < 4; ++a)
#pragma unroll
    for (int r = 0; r < 4; ++r) {
      li16[a * 4 + r] = labels[i0 + a * 16 + quad * 4 + r];
      ps16[a * 4 + r] = 0.0f;
      ns16[a * 4 + r] = 0.0f;
    }

  const float C0 = -5.0f + 1e-7f;  // s = 5g - 5 + 1e-7 (static shift S=10)

  __syncthreads();  // the ONLY barrier: A staging visible to all waves

  for (int jt = 0; jt < 8; ++jt) {
    const int j0 = j0s + jt * JT;
    int lj[4], gj[4];
    const unsigned short* bp[4];  // per-b base: row gj[b], this lane's quad k8
#pragma unroll
    for (int b = 0; b < 4; ++b) {
      gj[b] = j0 + wave * 64 + b * 16 + c16;
      lj[b] = labels[gj[b]];
      bp[b] = Rb + (size_t)gj[b] * DDIM + quad * 8;
    }

    f32x4 acc[4][4];
#pragma unroll
    for (int a = 0; a < 4; ++a)
#pragma unroll
      for (int b = 0; b < 4; ++b) acc[a][b] = (f32x4)0.0f;

    // Barrier-free K sweep: B frags direct global->VGPR (immediate offsets,
    // ch*64B <= 960), A frags from LDS. Compiler pipelines via vmcnt.
#pragma unroll
    for (int ch = 0; ch < 16; ++ch) {
      s16x8 af[4], bfr[4];
#pragma unroll
      for (int b = 0; b < 4; ++b)
        bfr[b] = *(const s16x8*)(bp[b] + ch * BK);
#pragma unroll
      for (int a = 0; a < 4; ++a)
        af[a] = *(const s16x8*)(&As[ch][a * 16 + c16][quad * 8]);
#pragma unroll
      for (int a = 0; a < 4; ++a)
#pragma unroll
        for (int b = 0; b < 4; ++b)
          acc[a][b] = __builtin_amdgcn_mfma_f32_16x16x32_bf16(af[a], bfr[b],
                                                              acc[a][b], 0, 0, 0);
    }

    // Fold this j-tile into register row sums (no atomics).
#pragma unroll
    for (int a = 0; a < 4; ++a) {
#pragma unroll
      for (int r = 0; r < 4; ++r) {
        const int gi = i0 + a * 16 + quad * 4 + r;
        const int li = li16[a * 4 + r];
        float ps = 0.0f, ns = 0.0f;
#pragma unroll
        for (int b = 0; b < 4; ++b) {
          const float g = acc[a][b][r];
          const float sv = fmaf(g, 5.0f, C0);
          const float ev = __expf(sv);
          const bool same = (li == lj[b]);
          ps += (same && gi != gj[b]) ? sv : 0.0f;
          ns += same ? 0.0f : ev;
        }
        ps16[a * 4 + r] += ps;
        ns16[a * 4 + r] += ns;
      }
    }
  }

  // ---- Block epilogue: reduce per-lane sums -> 64 rows, 2 atomics each.
  float* rp = red;       // 64 floats
  float* rn = red + 64;
  if (tid < 128) red[tid] = 0.0f;
  __syncthreads();
#pragma unroll
  for (int a = 0; a < 4; ++a) {
#pragma unroll
    for (int r = 0; r < 4; ++r) {
      float ps = ps16[a * 4 + r], ns = ns16[a * 4 + r];
#pragma unroll
      for (int m = 1; m < 16; m <<= 1) {  // reduce across the 16 c16 lanes
        ps += __shfl_xor(ps, m);
        ns += __shfl_xor(ns, m);
      }
      if (c16 == 0) {  // 4-way wave contention, once per block: trivial
        atomicAdd(&rp[a * 16 + quad * 4 + r], ps);
        atomicAdd(&rn[a * 16 + quad * 4 + r], ns);
      }
    }
  }
  __syncthreads();
  if (tid < 64) {
    atomicAdd(&row_pos[i0 + tid], rp[tid]);   // 4 adds per address chip-wide
    atomicAdd(&row_neg[i0 + tid], rn[tid]);
  }
}

__global__ void __launch_bounds__(512) k_final(
    const float* __restrict__ row_pos, const float* __restrict__ row_neg,
    const int* __restrict__ labels, const int* __restrict__ cnt,
    float* __restrict__ out) {
  __shared__ float ssum[8];
  __shared__ float scnt[8];
  const int tid = threadIdx.x;
  float lsum = 0.0f, lcnt = 0.0f;
  for (int i = tid; i < NROW; i += 512) {
    const float c = (float)(cnt[labels[i]] - 1);
    const float pos = row_pos[i] / (c + 1e-8f);
    const float loss = -pos + logf(row_neg[i] + 1e-8f);
    if (loss > 0.0f) { lsum += loss; lcnt += 1.0f; }
  }
#pragma unroll
  for (int m = 1; m < 64; m <<= 1) {
    lsum += __shfl_xor(lsum, m);
    lcnt += __shfl_xor(lcnt, m);
  }
  if ((tid & 63) == 0) { ssum[tid >> 6] = lsum; scnt[tid >> 6] = lcnt; }
  __syncthreads();
  if (tid == 0) {
    float S = 0.0f, C = 0.0f;
#pragma unroll
    for (int w = 0; w < 8; ++w) { S += ssum[w]; C += scnt[w]; }
    out[0] = S / (C + 1e-8f);
  }
}

extern "C" void kernel_launch(void* const* d_in, const int* in_sizes, int n_in,
                              void* d_out, int out_size, void* d_ws, size_t ws_size,
                              hipStream_t stream) {
  const float* reps = (const float*)d_in[0];
  const int* labels = (const int*)d_in[1];
  float* out = (float*)d_out;
  char* ws = (char*)d_ws;
  // ws layout: Rb (bf16 normalized reps, 8 MiB) | row_pos | row_neg | cnt
  unsigned short* Rb = (unsigned short*)ws;
  float* row_pos = (float*)(ws + (size_t)NROW * DDIM * 2);
  float* row_neg = row_pos + NROW;
  int* cnt = (int*)(row_neg + NROW);

  // row_pos | row_neg | cnt are contiguous: one async memset zeroes all three.
  (void)hipMemsetAsync(row_pos, 0, (size_t)(2 * NROW + NCLS) * 4, stream);
  k_prep<<<NROW / 4, 256, 0, stream>>>(reps, labels, Rb, cnt);
  k_row<<<512, 256, 0, stream>>>(Rb, labels, row_pos, row_neg);
  k_final<<<1, 512, 0, stream>>>(row_pos, row_neg, labels, cnt, out);
  (void)in_sizes; (void)n_in; (void)out_size; (void)ws_size;
}

// Round 10
// 201.236 us; speedup vs baseline: 1.2506x; 1.2314x over previous
//
#include <hip/hip_runtime.h>

// SupProtoConLoss on MI355X — round 10.
// R9 post-mortem: barrier-free direct-B K-loop is the best per-wave engine yet
// (1.41x R7 per-wave), but full unroll hoisted B-loads -> VGPR 244 + 64 AGPR
// > 256 -> 1 block/CU. Fix: explicit depth-2 register pipeline (#pragma
// unroll 1): 32 B-frag regs in flight, VGPR target <=190 -> 2 blocks/CU.
// Overhead trim (stable ~90us non-k_row across rounds): memset folded into
// k_prep (zero row sums there; stream order protects k_row's atomics), label
// histogram moved into k_final (LDS) -> cnt eliminated, 3 graph nodes.

#define NROW 8192
#define DDIM 512
#define NCLS 100
#define PANEL 64
#define JT 256  // cols per j-tile (4 waves x 64)
#define BK 32

typedef float f32x4 __attribute__((ext_vector_type(4)));
typedef short s16x8 __attribute__((ext_vector_type(8)));

#define GLOBAL_AS __attribute__((address_space(1)))
#define LDS_AS __attribute__((address_space(3)))

__device__ __forceinline__ unsigned short f2bf(float x) {
  unsigned int u = __builtin_bit_cast(unsigned int, x);
  u += 0x7FFFu + ((u >> 16) & 1u);  // round-to-nearest-even
  return (unsigned short)(u >> 16);
}

// One wave per row: L2-norm, scale, cast to bf16. Also zeroes row_pos/row_neg
// (16384 floats over 2048 blocks) — k_row only touches them afterwards.
__global__ void __launch_bounds__(256) k_prep(
    const float* __restrict__ reps, float* __restrict__ row_pos,
    unsigned short* __restrict__ Rb) {
  const int wave = threadIdx.x >> 6;
  const int lane = threadIdx.x & 63;
  const int row = blockIdx.x * 4 + wave;
  if (threadIdx.x < 8) row_pos[blockIdx.x * 8 + threadIdx.x] = 0.0f;
  const float* r = reps + (size_t)row * DDIM;
  float4 v0 = *(const float4*)(r + lane * 4);
  float4 v1 = *(const float4*)(r + 256 + lane * 4);
  float ss = v0.x * v0.x + v0.y * v0.y + v0.z * v0.z + v0.w * v0.w +
             v1.x * v1.x + v1.y * v1.y + v1.z * v1.z + v1.w * v1.w;
#pragma unroll
  for (int m = 1; m < 64; m <<= 1) ss += __shfl_xor(ss, m);
  const float scale = 1.0f / sqrtf(ss);  // norms ~22.6; 1e-8 clamp unreachable
  ushort4 a, b;
  a.x = f2bf(v0.x * scale); a.y = f2bf(v0.y * scale);
  a.z = f2bf(v0.z * scale); a.w = f2bf(v0.w * scale);
  b.x = f2bf(v1.x * scale); b.y = f2bf(v1.y * scale);
  b.z = f2bf(v1.z * scale); b.w = f2bf(v1.w * scale);
  *(ushort4*)(Rb + (size_t)row * DDIM + lane * 4) = a;
  *(ushort4*)(Rb + (size_t)row * DDIM + 256 + lane * 4) = b;
}

// Block = 64-row panel (p = bx>>2) x 2048-col slice (s = bx&3), 4 waves.
// Wave tile per jt: 64 rows x 64 cols = 4a x 4b of 16x16x32 MFMA.
__global__ void __launch_bounds__(256) k_row(
    const unsigned short* __restrict__ Rb, const int* __restrict__ labels,
    float* __restrict__ row_pos, float* __restrict__ row_neg) {
  const int bx = blockIdx.x;
  const int p = bx >> 2;   // row panel 0..127
  const int s = bx & 3;    // j slice 0..3 (fixed per XCD under %8 dispatch)
  const int i0 = p * PANEL;
  const int j0s = s * 2048;

  // As chunk-major [ch][row][k-in-chunk] (row stride 64B). 64 KB.
  __shared__ __attribute__((aligned(16))) unsigned short As[16][PANEL][BK];
  __shared__ float red[128];  // epilogue scratch

  const int tid = threadIdx.x;
  const int lane = tid & 63;
  const int wave = tid >> 6;
  const int quad = lane >> 4, c16 = lane & 15;

  // ---- Stage A panel once, chunk-major: 64 instrs, 16 per wave.
#pragma unroll
  for (int t = 0; t < 16; ++t) {
    const int ii = wave * 16 + t;        // wave-uniform, 0..63
    const int ch = ii >> 2;
    const int rg = (ii & 3) * 16;
    const unsigned short* src =
        Rb + (size_t)(i0 + rg + (lane >> 2)) * DDIM + ch * BK + (lane & 3) * 8;
    __builtin_amdgcn_global_load_lds(
        (GLOBAL_AS void*)const_cast<unsigned short*>(src),
        (LDS_AS void*)(&As[ch][rg][0]), 16, 0, 0);
  }

  // Per-lane row labels and running row sums (live across the whole sweep).
  int li16[16];
  float ps16[16], ns16[16];
#pragma unroll
  for (int a = 0; a < 4; ++a)
#pragma unroll
    for (int r = 0; r < 4; ++r) {
      li16[a * 4 + r] = labels[i0 + a * 16 + quad * 4 + r];
      ps16[a * 4 + r] = 0.0f;
      ns16[a * 4 + r] = 0.0f;
    }

  const float C0 = -5.0f + 1e-7f;  // s = 5g - 5 + 1e-7 (static shift S=10)

  __syncthreads();  // the ONLY barrier before epilogue: A staging visible

  for (int jt = 0; jt < 8; ++jt) {
    const int j0 = j0s + jt * JT;
    int lj[4], gj[4];
    const unsigned short* bp[4];  // per-b cursor: row gj[b], this lane's k8
#pragma unroll
    for (int b = 0; b < 4; ++b) {
      gj[b] = j0 + wave * 64 + b * 16 + c16;
      lj[b] = labels[gj[b]];
      bp[b] = Rb + (size_t)gj[b] * DDIM + quad * 8;
    }

    f32x4 acc[4][4];
#pragma unroll
    for (int a = 0; a < 4; ++a)
#pragma unroll
      for (int b = 0; b < 4; ++b) acc[a][b] = (f32x4)0.0f;

    // Depth-2 register pipeline, barrier-free. In-flight B regs = 32.
    s16x8 bcur[4], bnxt[4];
#pragma unroll
    for (int b = 0; b < 4; ++b) bcur[b] = *(const s16x8*)bp[b];

    const unsigned short* ap = &As[0][c16][0] + quad * 8;  // +1024B per a

#pragma unroll 1
    for (int ch = 0; ch < 16; ++ch) {
      if (ch < 15) {
#pragma unroll
        for (int b = 0; b < 4; ++b) {
          bp[b] += BK;
          bnxt[b] = *(const s16x8*)bp[b];
        }
      }
      s16x8 af[4];
#pragma unroll
      for (int a = 0; a < 4; ++a)
        af[a] = *(const s16x8*)(ap + a * 16 * BK);
      ap += PANEL * BK;  // next chunk plane (4096 B)
#pragma unroll
      for (int a = 0; a < 4; ++a)
#pragma unroll
        for (int b = 0; b < 4; ++b)
          acc[a][b] = __builtin_amdgcn_mfma_f32_16x16x32_bf16(af[a], bcur[b],
                                                              acc[a][b], 0, 0, 0);
      if (ch < 15) {
#pragma unroll
        for (int b = 0; b < 4; ++b) bcur[b] = bnxt[b];
      }
    }

    // Fold this j-tile into register row sums (no atomics).
#pragma unroll
    for (int a = 0; a < 4; ++a) {
#pragma unroll
      for (int r = 0; r < 4; ++r) {
        const int gi = i0 + a * 16 + quad * 4 + r;
        const int li = li16[a * 4 + r];
        float ps = 0.0f, ns = 0.0f;
#pragma unroll
        for (int b = 0; b < 4; ++b) {
          const float g = acc[a][b][r];
          const float sv = fmaf(g, 5.0f, C0);
          const float ev = __expf(sv);
          const bool same = (li == lj[b]);
          ps += (same && gi != gj[b]) ? sv : 0.0f;
          ns += same ? 0.0f : ev;
        }
        ps16[a * 4 + r] += ps;
        ns16[a * 4 + r] += ns;
      }
    }
  }

  // ---- Block epilogue: reduce per-lane sums -> 64 rows, 2 atomics each.
  float* rp = red;       // 64 floats
  float* rn = red + 64;
  if (tid < 128) red[tid] = 0.0f;
  __syncthreads();
#pragma unroll
  for (int a = 0; a < 4; ++a) {
#pragma unroll
    for (int r = 0; r < 4; ++r) {
      float ps = ps16[a * 4 + r], ns = ns16[a * 4 + r];
#pragma unroll
      for (int m = 1; m < 16; m <<= 1) {  // reduce across the 16 c16 lanes
        ps += __shfl_xor(ps, m);
        ns += __shfl_xor(ns, m);
      }
      if (c16 == 0) {  // 4-way wave contention, once per block: trivial
        atomicAdd(&rp[a * 16 + quad * 4 + r], ps);
        atomicAdd(&rn[a * 16 + quad * 4 + r], ns);
      }
    }
  }
  __syncthreads();
  if (tid < 64) {
    atomicAdd(&row_pos[i0 + tid], rp[tid]);   // 4 adds per address chip-wide
    atomicAdd(&row_neg[i0 + tid], rn[tid]);
  }
}

// LDS label histogram + loss reduction (cnt array eliminated).
__global__ void __launch_bounds__(512) k_final(
    const float* __restrict__ row_pos, const float* __restrict__ row_neg,
    const int* __restrict__ labels, float* __restrict__ out) {
  __shared__ int hcnt[NCLS];
  __shared__ float ssum[8];
  __shared__ float scnt[8];
  const int tid = threadIdx.x;
  if (tid < NCLS) hcnt[tid] = 0;
  __syncthreads();
  for (int i = tid; i < NROW; i += 512) atomicAdd(&hcnt[labels[i]], 1);
  __syncthreads();
  float lsum = 0.0f, lcnt = 0.0f;
  for (int i = tid; i < NROW; i += 512) {
    const float c = (float)(hcnt[labels[i]] - 1);
    const float pos = row_pos[i] / (c + 1e-8f);
    const float loss = -pos + logf(row_neg[i] + 1e-8f);
    if (loss > 0.0f) { lsum += loss; lcnt += 1.0f; }
  }
#pragma unroll
  for (int m = 1; m < 64; m <<= 1) {
    lsum += __shfl_xor(lsum, m);
    lcnt += __shfl_xor(lcnt, m);
  }
  if ((tid & 63) == 0) { ssum[tid >> 6] = lsum; scnt[tid >> 6] = lcnt; }
  __syncthreads();
  if (tid == 0) {
    float S = 0.0f, C = 0.0f;
#pragma unroll
    for (int w = 0; w < 8; ++w) { S += ssum[w]; C += scnt[w]; }
    out[0] = S / (C + 1e-8f);
  }
}

extern "C" void kernel_launch(void* const* d_in, const int* in_sizes, int n_in,
                              void* d_out, int out_size, void* d_ws, size_t ws_size,
                              hipStream_t stream) {
  const float* reps = (const float*)d_in[0];
  const int* labels = (const int*)d_in[1];
  float* out = (float*)d_out;
  char* ws = (char*)d_ws;
  // ws layout: Rb (bf16 normalized reps, 8 MiB) | row_pos | row_neg
  unsigned short* Rb = (unsigned short*)ws;
  float* row_pos = (float*)(ws + (size_t)NROW * DDIM * 2);
  float* row_neg = row_pos + NROW;

  k_prep<<<NROW / 4, 256, 0, stream>>>(reps, row_pos, Rb);
  k_row<<<512, 256, 0, stream>>>(Rb, labels, row_pos, row_neg);
  k_final<<<1, 512, 0, stream>>>(row_pos, row_neg, labels, out);
  (void)in_sizes; (void)n_in; (void)out_size; (void)ws_size;
}

// Round 11
// 178.959 us; speedup vs baseline: 1.4063x; 1.1245x over previous
//
#include <hip/hip_runtime.h>

// SupProtoConLoss on MI355X — round 11.
// League table: R7 k_row (LDS-B, 2-barrier) = 110.5us best; R9 direct-B best
// per-wave but 1 block/CU (VGPR 244); R10 depth-2 pipeline starved (4 loads in
// flight) + mov tax. R10's 3-node launch trim banked ~32us (overhead 92->60).
// Round 11 = R7 k_row with the drain COVERED + R10 trim:
//   read frags(ch) -> barrier(reads drained) -> issue stage(it+1) into Bs ->
//   16 MFMA (+ jt-end fold) -> barrier(vmcnt drain, now covered by MFMA).
// Same instructions as R7, reordered; flat 128-iter loop; Bs reused as
// epilogue scratch (LDS exactly 81920 -> 2 blocks/CU preserved).

#define NROW 8192
#define DDIM 512
#define NCLS 100
#define PANEL 64
#define JT 256  // cols per j-tile (4 waves x 64)
#define BK 32

typedef float f32x4 __attribute__((ext_vector_type(4)));
typedef short s16x8 __attribute__((ext_vector_type(8)));

#define GLOBAL_AS __attribute__((address_space(1)))
#define LDS_AS __attribute__((address_space(3)))

__device__ __forceinline__ unsigned short f2bf(float x) {
  unsigned int u = __builtin_bit_cast(unsigned int, x);
  u += 0x7FFFu + ((u >> 16) & 1u);  // round-to-nearest-even
  return (unsigned short)(u >> 16);
}

// One wave per row: L2-norm, scale, cast to bf16. Also zeroes row_pos/row_neg
// (16384 floats over 2048 blocks) — k_row only touches them afterwards.
__global__ void __launch_bounds__(256) k_prep(
    const float* __restrict__ reps, float* __restrict__ row_pos,
    unsigned short* __restrict__ Rb) {
  const int wave = threadIdx.x >> 6;
  const int lane = threadIdx.x & 63;
  const int row = blockIdx.x * 4 + wave;
  if (threadIdx.x < 8) row_pos[blockIdx.x * 8 + threadIdx.x] = 0.0f;
  const float* r = reps + (size_t)row * DDIM;
  float4 v0 = *(const float4*)(r + lane * 4);
  float4 v1 = *(const float4*)(r + 256 + lane * 4);
  float ss = v0.x * v0.x + v0.y * v0.y + v0.z * v0.z + v0.w * v0.w +
             v1.x * v1.x + v1.y * v1.y + v1.z * v1.z + v1.w * v1.w;
#pragma unroll
  for (int m = 1; m < 64; m <<= 1) ss += __shfl_xor(ss, m);
  const float scale = 1.0f / sqrtf(ss);  // norms ~22.6; 1e-8 clamp unreachable
  ushort4 a, b;
  a.x = f2bf(v0.x * scale); a.y = f2bf(v0.y * scale);
  a.z = f2bf(v0.z * scale); a.w = f2bf(v0.w * scale);
  b.x = f2bf(v1.x * scale); b.y = f2bf(v1.y * scale);
  b.z = f2bf(v1.z * scale); b.w = f2bf(v1.w * scale);
  *(ushort4*)(Rb + (size_t)row * DDIM + lane * 4) = a;
  *(ushort4*)(Rb + (size_t)row * DDIM + 256 + lane * 4) = b;
}

// Block = 64-row panel (p = bx>>2) x 2048-col slice (s = bx&3), 4 waves.
// Wave tile per jt: 64 rows x 64 cols = 4a x 4b of 16x16x32 MFMA.
__global__ void __launch_bounds__(256) k_row(
    const unsigned short* __restrict__ Rb, const int* __restrict__ labels,
    float* __restrict__ row_pos, float* __restrict__ row_neg) {
  const int bx = blockIdx.x;
  const int p = bx >> 2;   // row panel 0..127
  const int s = bx & 3;    // j slice 0..3 (fixed per XCD under %8 dispatch)
  const int i0 = p * PANEL;
  const int j0s = s * 2048;

  // As chunk-major [ch][row][k-in-chunk] (row stride 64B), 64 KB; Bs 16 KB.
  // Total 81920 B exactly -> 2 blocks/CU. Bs doubles as epilogue scratch.
  __shared__ __attribute__((aligned(16))) unsigned short As[16][PANEL][BK];
  __shared__ __attribute__((aligned(16))) unsigned short Bs[JT * BK];

  const int tid = threadIdx.x;
  const int lane = tid & 63;
  const int wave = tid >> 6;
  const int quad = lane >> 4, c16 = lane & 15;

  // ---- Stage A panel once, chunk-major: 64 instrs, 16 per wave.
#pragma unroll
  for (int t = 0; t < 16; ++t) {
    const int ii = wave * 16 + t;        // wave-uniform, 0..63
    const int ch = ii >> 2;
    const int rg = (ii & 3) * 16;
    const unsigned short* src =
        Rb + (size_t)(i0 + rg + (lane >> 2)) * DDIM + ch * BK + (lane & 3) * 8;
    __builtin_amdgcn_global_load_lds(
        (GLOBAL_AS void*)const_cast<unsigned short*>(src),
        (LDS_AS void*)(&As[ch][rg][0]), 16, 0, 0);
  }

  // B-stage for flat iteration it (jt = it>>4, ch = it&15): 1024 16B chunks,
  // 4 instrs per wave.
  auto stageB = [&](int it) {
    const int j0 = j0s + (it >> 4) * JT;
    const int ch = it & 15;
#pragma unroll
    for (int t = 0; t < 4; ++t) {
      const int cb = wave * 64 + t * 256;  // wave-uniform chunk base
      const int sl = cb + lane;            // jcol = sl>>2, kc = sl&3
      const unsigned short* src =
          Rb + (size_t)(j0 + (sl >> 2)) * DDIM + ch * BK + (sl & 3) * 8;
      __builtin_amdgcn_global_load_lds(
          (GLOBAL_AS void*)const_cast<unsigned short*>(src),
          (LDS_AS void*)(Bs + cb * 8), 16, 0, 0);
    }
  };

  // Per-lane row labels and running row sums (live across the whole sweep).
  int li16[16];
  float ps16[16], ns16[16];
#pragma unroll
  for (int a = 0; a < 4; ++a)
#pragma unroll
    for (int r = 0; r < 4; ++r) {
      li16[a * 4 + r] = labels[i0 + a * 16 + quad * 4 + r];
      ps16[a * 4 + r] = 0.0f;
      ns16[a * 4 + r] = 0.0f;
    }

  const float C0 = -5.0f + 1e-7f;  // s = 5g - 5 + 1e-7 (static shift S=10)

  stageB(0);
  __syncthreads();  // A panel + B(0) visible

  f32x4 acc[4][4];
  int lj[4], gj[4];

#pragma unroll 1
  for (int it = 0; it < 128; ++it) {
    const int ch = it & 15;
    if (ch == 0) {
      const int j0 = j0s + (it >> 4) * JT;
#pragma unroll
      for (int b = 0; b < 4; ++b) {
        gj[b] = j0 + wave * 64 + b * 16 + c16;
        lj[b] = labels[gj[b]];
      }
#pragma unroll
      for (int a = 0; a < 4; ++a)
#pragma unroll
        for (int b = 0; b < 4; ++b) acc[a][b] = (f32x4)0.0f;
    }

    // Read this iteration's fragments BEFORE the overwrite barrier.
    s16x8 af[4], bfr[4];
#pragma unroll
    for (int a = 0; a < 4; ++a)
      af[a] = *(const s16x8*)(&As[ch][a * 16 + c16][quad * 8]);
#pragma unroll
    for (int b = 0; b < 4; ++b)
      bfr[b] = *(const s16x8*)(Bs + (wave * 64 + b * 16 + c16) * BK + quad * 8);

    __syncthreads();  // all waves' Bs reads drained (lgkm) — Bs reusable
    if (it + 1 < 128) stageB(it + 1);

    // MFMA (and at jt-end the fold) cover the stage latency before the drain.
#pragma unroll
    for (int a = 0; a < 4; ++a)
#pragma unroll
      for (int b = 0; b < 4; ++b)
        acc[a][b] = __builtin_amdgcn_mfma_f32_16x16x32_bf16(af[a], bfr[b],
                                                            acc[a][b], 0, 0, 0);

    if (ch == 15) {
#pragma unroll
      for (int a = 0; a < 4; ++a) {
#pragma unroll
        for (int r = 0; r < 4; ++r) {
          const int gi = i0 + a * 16 + quad * 4 + r;
          const int li = li16[a * 4 + r];
          float ps = 0.0f, ns = 0.0f;
#pragma unroll
          for (int b = 0; b < 4; ++b) {
            const float g = acc[a][b][r];
            const float sv = fmaf(g, 5.0f, C0);
            const float ev = __expf(sv);
            const bool same = (li == lj[b]);
            ps += (same && gi != gj[b]) ? sv : 0.0f;
            ns += same ? 0.0f : ev;
          }
          ps16[a * 4 + r] += ps;
          ns16[a * 4 + r] += ns;
        }
      }
    }

    __syncthreads();  // drain stage(it+1) — covered by the MFMA phase above
  }

  // ---- Block epilogue: reduce per-lane sums -> 64 rows, 2 atomics each.
  // Bs reused as scratch (keeps LDS at 81920 -> 2 blocks/CU).
  float* rp = (float*)Bs;   // 64 floats
  float* rn = rp + 64;
  if (tid < 128) rp[tid] = 0.0f;
  __syncthreads();
#pragma unroll
  for (int a = 0; a < 4; ++a) {
#pragma unroll
    for (int r = 0; r < 4; ++r) {
      float ps = ps16[a * 4 + r], ns = ns16[a * 4 + r];
#pragma unroll
      for (int m = 1; m < 16; m <<= 1) {  // reduce across the 16 c16 lanes
        ps += __shfl_xor(ps, m);
        ns += __shfl_xor(ns, m);
      }
      if (c16 == 0) {  // 4-way wave contention, once per block: trivial
        atomicAdd(&rp[a * 16 + quad * 4 + r], ps);
        atomicAdd(&rn[a * 16 + quad * 4 + r], ns);
      }
    }
  }
  __syncthreads();
  if (tid < 64) {
    atomicAdd(&row_pos[i0 + tid], rp[tid]);   // 4 adds per address chip-wide
    atomicAdd(&row_neg[i0 + tid], rn[tid]);
  }
}

// LDS label histogram + loss reduction (cnt array eliminated).
__global__ void __launch_bounds__(512) k_final(
    const float* __restrict__ row_pos, const float* __restrict__ row_neg,
    const int* __restrict__ labels, float* __restrict__ out) {
  __shared__ int hcnt[NCLS];
  __shared__ float ssum[8];
  __shared__ float scnt[8];
  const int tid = threadIdx.x;
  if (tid < NCLS) hcnt[tid] = 0;
  __syncthreads();
  for (int i = tid; i < NROW; i += 512) atomicAdd(&hcnt[labels[i]], 1);
  __syncthreads();
  float lsum = 0.0f, lcnt = 0.0f;
  for (int i = tid; i < NROW; i += 512) {
    const float c = (float)(hcnt[labels[i]] - 1);
    const float pos = row_pos[i] / (c + 1e-8f);
    const float loss = -pos + logf(row_neg[i] + 1e-8f);
    if (loss > 0.0f) { lsum += loss; lcnt += 1.0f; }
  }
#pragma unroll
  for (int m = 1; m < 64; m <<= 1) {
    lsum += __shfl_xor(lsum, m);
    lcnt += __shfl_xor(lcnt, m);
  }
  if ((tid & 63) == 0) { ssum[tid >> 6] = lsum; scnt[tid >> 6] = lcnt; }
  __syncthreads();
  if (tid == 0) {
    float S = 0.0f, C = 0.0f;
#pragma unroll
    for (int w = 0; w < 8; ++w) { S += ssum[w]; C += scnt[w]; }
    out[0] = S / (C + 1e-8f);
  }
}

extern "C" void kernel_launch(void* const* d_in, const int* in_sizes, int n_in,
                              void* d_out, int out_size, void* d_ws, size_t ws_size,
                              hipStream_t stream) {
  const float* reps = (const float*)d_in[0];
  const int* labels = (const int*)d_in[1];
  float* out = (float*)d_out;
  char* ws = (char*)d_ws;
  // ws layout: Rb (bf16 normalized reps, 8 MiB) | row_pos | row_neg
  unsigned short* Rb = (unsigned short*)ws;
  float* row_pos = (float*)(ws + (size_t)NROW * DDIM * 2);
  float* row_neg = row_pos + NROW;

  k_prep<<<NROW / 4, 256, 0, stream>>>(reps, row_pos, Rb);
  k_row<<<512, 256, 0, stream>>>(Rb, labels, row_pos, row_neg);
  k_final<<<1, 512, 0, stream>>>(row_pos, row_neg, labels, out);
  (void)in_sizes; (void)n_in; (void)out_size; (void)ws_size;
}